// Round 2
// baseline (264.078 us; speedup 1.0000x reference)
//
#include <hip/hip_runtime.h>
#include <stdint.h>

#define B_ 8
#define T_ 512
#define M_ 16
#define D_ 128
#define P_ 256
#define H_ 8
#define E_ 32
#define G_ (B_*M_*H_)   // 1024 (b,m,h) groups

typedef __attribute__((ext_vector_type(8))) short  short8;
typedef __attribute__((ext_vector_type(4))) short  short4v;
typedef __attribute__((ext_vector_type(4))) float  float4v;

#define MFMA16(a,b,c) __builtin_amdgcn_mfma_f32_16x16x32_bf16(a,b,c,0,0,0)
#define EXP2F(x) __builtin_amdgcn_exp2f(x)

static __device__ __forceinline__ unsigned short f2bf(float x){
  unsigned int u = __builtin_bit_cast(unsigned int, x);
  u += 0x7FFFu + ((u >> 16) & 1u);           // RNE
  return (unsigned short)(u >> 16);
}

static __device__ __forceinline__ short8 pack8(float4v a, float4v b){
  short8 r;
  r[0]=(short)f2bf(a[0]); r[1]=(short)f2bf(a[1]); r[2]=(short)f2bf(a[2]); r[3]=(short)f2bf(a[3]);
  r[4]=(short)f2bf(b[0]); r[5]=(short)f2bf(b[1]); r[6]=(short)f2bf(b[2]); r[7]=(short)f2bf(b[3]);
  return r;
}

// ---------------- kernel 0: W (D,P) fp32 -> WT[z][p][d] bf16 ----------------
__global__ void prep_wt(const float* __restrict__ Wq, const float* __restrict__ Wk,
                        const float* __restrict__ Wv, uint16_t* __restrict__ WT){
  int idx = blockIdx.x*256 + threadIdx.x;    // 3*256*128 = 98304 total
  int d = idx & (D_-1);
  int p = (idx >> 7) & (P_-1);
  int z = idx >> 15;
  const float* W = (z==0) ? Wq : (z==1) ? Wk : Wv;
  WT[idx] = f2bf(W[d*P_ + p]);
}

// ---------------- kernel 1: QKV projection (bf16 MFMA, no LDS) --------------
// out layout: QKV[z][g][t][e] bf16,  g=(b*M+m)*H+h
__global__ __launch_bounds__(256) void qkv_gemm(
    const float* __restrict__ inp, const uint16_t* __restrict__ WT,
    const float* __restrict__ bq, const float* __restrict__ bk,
    const float* __restrict__ bv, uint16_t* __restrict__ QKV){
  const int rb   = blockIdx.x;          // 64-row block (1024 blocks)
  const int z    = blockIdx.y;          // q/k/v
  const int tid  = threadIdx.x;
  const int wave = tid >> 6, lane = tid & 63;
  const int q4 = lane >> 4, c = lane & 15;

  const float* bias = (z==0) ? bq : (z==1) ? bk : bv;
  uint16_t* Out = QKV + (size_t)z * ((size_t)G_*T_*E_);
  const uint16_t* WTz = WT + (size_t)z * P_ * D_;
  const int row0 = rb*64;
  const int colbase = wave*64;

  // B-fragments: W^T[p][d], 16B contiguous along d  (L2-resident, read once)
  short8 bfrag[4][4];
  for (int nj=0; nj<4; nj++){
    int p = colbase + nj*16 + c;
    for (int kc=0; kc<4; kc++)
      bfrag[nj][kc] = *(const short8*)(WTz + (size_t)p*D_ + kc*32 + q4*8);
  }

  float4v zf = {0.f,0.f,0.f,0.f};
  float4v acc[4][4];
  for (int i=0;i<4;i++) for (int j=0;j<4;j++) acc[i][j] = zf;

  for (int kc=0; kc<4; kc++){
    short8 afrag[4];
    for (int ti=0; ti<4; ti++){
      const float* src = inp + (size_t)(row0 + ti*16 + c)*D_ + kc*32 + q4*8;
      float4v x0 = *(const float4v*)src;
      float4v x1 = *(const float4v*)(src+4);
      afrag[ti] = pack8(x0, x1);
    }
    for (int ti=0; ti<4; ti++)
      for (int nj=0; nj<4; nj++)
        acc[ti][nj] = MFMA16(afrag[ti], bfrag[nj][kc], acc[ti][nj]);
  }

  // epilogue: +bias, ->bf16, scatter to [g][t][e]
  for (int nj=0; nj<4; nj++){
    int p = colbase + nj*16 + c;
    float bvv = bias[p];
    int h = p >> 5, e = p & 31;
    for (int ti=0; ti<4; ti++){
      for (int r=0; r<4; r++){
        int row = row0 + ti*16 + q4*4 + r;       // = (b*T+t)*M + m
        int m = row & (M_-1);
        int bt = row >> 4;                        // b*T + t
        int t = bt & (T_-1);
        int b = bt >> 9;
        int g = (b*M_ + m)*H_ + h;
        Out[((size_t)g*T_ + t)*E_ + e] = f2bf(acc[ti][nj][r] + bvv);
      }
    }
  }
}

// ---------------- kernel 2: masked attention per (g, t-half) ---------------
// S^T = K.Q^T (C-layout reg axis = s) -> exp2 -> PT LDS -> O = P.V
#define SPAD 40    // PT row stride (bf16)
#define VPAD 520   // Vt row stride (bf16)

__global__ __launch_bounds__(256) void attn(
    const uint16_t* __restrict__ QKV, const int* __restrict__ mask,
    float* __restrict__ out){
  __shared__ __align__(16) uint16_t Vt[E_*VPAD];      // 33,280 B  V^T[e][s]
  __shared__ __align__(16) float    maskc[T_];        //  2,048 B  0 / -1e30
  __shared__ __align__(16) uint16_t PT[4*64*SPAD];    // 20,480 B  per-wave P[t][s]
  __shared__ __align__(16) float    lrow[4*64];       //  1,024 B  1/l per t

  const int g    = blockIdx.x >> 1;
  const int half = blockIdx.x & 1;
  const int h = g & (H_-1), bm = g >> 3, m = bm & (M_-1), b = bm >> 4;
  const int tid = threadIdx.x;
  const int wave = tid >> 6, lane = tid & 63;
  const int q4 = lane >> 4, c = lane & 15;

  const uint16_t* Q = QKV + (size_t)g*T_*E_;
  const uint16_t* K = QKV + (size_t)G_*T_*E_   + (size_t)g*T_*E_;
  const uint16_t* V = QKV + (size_t)2*G_*T_*E_ + (size_t)g*T_*E_;

  for (int s = tid; s < T_; s += 256)
    maskc[s] = mask[(b*T_ + s)*M_ + m] ? 0.0f : -1e30f;
  for (int idx = tid; idx < T_*E_; idx += 256){
    int s = idx >> 5, e = idx & (E_-1);
    Vt[e*VPAD + s] = V[idx];
  }
  __syncthreads();

  const int t0 = half*256 + wave*64;
  short8 qfrag[4];                       // B-operand: Q[t][e], k=e contiguous
  for (int tj=0; tj<4; tj++)
    qfrag[tj] = *(const short8*)(Q + (size_t)(t0 + tj*16 + c)*E_ + q4*8);

  float4v zf = {0.f,0.f,0.f,0.f};
  float4v O[4][2];
  for (int i=0;i<4;i++){ O[i][0]=zf; O[i][1]=zf; }
  float lsum[4] = {0.f,0.f,0.f,0.f};
  uint16_t* PTw = PT + wave*64*SPAD;
  const float c2 = 0.2550332772062413f;  // log2(e)/sqrt(E)

  for (int sb = 0; sb < 16; sb++){
    const int s0 = sb*32;
    short8 kfrag[2];                     // A-operand: K[s][e], k=e contiguous
    kfrag[0] = *(const short8*)(K + (size_t)(s0 + c)*E_ + q4*8);
    kfrag[1] = *(const short8*)(K + (size_t)(s0 + 16 + c)*E_ + q4*8);
    float4v mm0 = *(const float4v*)(&maskc[s0 + q4*4]);
    float4v mm1 = *(const float4v*)(&maskc[s0 + 16 + q4*4]);

    for (int si=0; si<2; si++){
      float4v mm = si ? mm1 : mm0;
      for (int tj=0; tj<4; tj++){
        float4v st = MFMA16(kfrag[si], qfrag[tj], zf);   // S^T: rows=s, cols=t
        float4v p;
        p[0] = EXP2F(st[0]*c2 + mm[0]);
        p[1] = EXP2F(st[1]*c2 + mm[1]);
        p[2] = EXP2F(st[2]*c2 + mm[2]);
        p[3] = EXP2F(st[3]*c2 + mm[3]);
        lsum[tj] += (p[0]+p[1]) + (p[2]+p[3]);
        short4v pk;
        pk[0]=(short)f2bf(p[0]); pk[1]=(short)f2bf(p[1]);
        pk[2]=(short)f2bf(p[2]); pk[3]=(short)f2bf(p[3]);
        *(short4v*)(PTw + (tj*16 + c)*SPAD + si*16 + q4*4) = pk;  // P[t][s]
      }
    }
    // O += P.V   (A = P[t][s] from LDS, B = V^T[e][s] from LDS)
    short8 vfrag0 = *(const short8*)(Vt + (size_t)c*VPAD        + s0 + q4*8);
    short8 vfrag1 = *(const short8*)(Vt + (size_t)(16+c)*VPAD   + s0 + q4*8);
    for (int ti=0; ti<4; ti++){
      short8 pfrag = *(const short8*)(PTw + (ti*16 + c)*SPAD + q4*8);
      O[ti][0] = MFMA16(pfrag, vfrag0, O[ti][0]);
      O[ti][1] = MFMA16(pfrag, vfrag1, O[ti][1]);
    }
  }

  // denominator: reduce quad-partials, broadcast 1/l via LDS
  for (int tj=0; tj<4; tj++){
    float v = lsum[tj];
    v += __shfl_xor(v, 16, 64);
    v += __shfl_xor(v, 32, 64);
    if (q4 == 0) lrow[wave*64 + tj*16 + c] = __builtin_amdgcn_rcpf(v);
  }
  for (int ti=0; ti<4; ti++){
    float4v linv = *(const float4v*)(&lrow[wave*64 + ti*16 + q4*4]);
    for (int ej=0; ej<2; ej++){
      int e = h*E_ + ej*16 + c;
      for (int r=0; r<4; r++){
        int t = t0 + ti*16 + q4*4 + r;
        out[(((size_t)b*T_ + t)*M_ + m)*P_ + e] = O[ti][ej][r] * linv[r];
      }
    }
  }
}

extern "C" void kernel_launch(void* const* d_in, const int* in_sizes, int n_in,
                              void* d_out, int out_size, void* d_ws, size_t ws_size,
                              hipStream_t stream){
  const float* inp = (const float*)d_in[0];
  const int*   msk = (const int*)  d_in[1];
  const float* Wq  = (const float*)d_in[2];
  const float* bq  = (const float*)d_in[3];
  const float* Wk  = (const float*)d_in[4];
  const float* bk  = (const float*)d_in[5];
  const float* Wv  = (const float*)d_in[6];
  const float* bv  = (const float*)d_in[7];
  float* out = (float*)d_out;

  uint16_t* WT  = (uint16_t*)d_ws;                       // 196,608 B
  uint16_t* QKV = (uint16_t*)((char*)d_ws + 196608);     // 3 * 32 MiB bf16

  prep_wt<<<dim3(384), dim3(256), 0, stream>>>(Wq, Wk, Wv, WT);
  qkv_gemm<<<dim3(1024,3), dim3(256), 0, stream>>>(inp, WT, bq, bk, bv, QKV);
  attn<<<dim3(2048), dim3(256), 0, stream>>>(QKV, msk, out);
}

// Round 4
// 250.348 us; speedup vs baseline: 1.0548x; 1.0548x over previous
//
#include <hip/hip_runtime.h>
#include <stdint.h>

#define B_ 8
#define T_ 512
#define M_ 16
#define D_ 128
#define P_ 256
#define H_ 8
#define E_ 32
#define G_ (B_*M_*H_)   // 1024 (b,m,h) groups

typedef __attribute__((ext_vector_type(8))) short  short8;
typedef __attribute__((ext_vector_type(4))) short  short4v;
typedef __attribute__((ext_vector_type(4))) float  float4v;
typedef __attribute__((ext_vector_type(2))) unsigned int uint2v;
typedef __attribute__((ext_vector_type(4))) unsigned int uint4v;

#define MFMA32(a,b,c) __builtin_amdgcn_mfma_f32_16x16x32_bf16(a,b,c,0,0,0)   // K=32, short8 ops
#define MFMA16(a,b,c) __builtin_amdgcn_mfma_f32_16x16x16bf16_1k(a,b,c,0,0,0) // K=16, short4 ops
#define EXP2F(x) __builtin_amdgcn_exp2f(x)

#define C2 0.2550332772062413f   // log2(e)/sqrt(E)

static __device__ __forceinline__ unsigned short f2bf(float x){
  unsigned int u = __builtin_bit_cast(unsigned int, x);
  u += 0x7FFFu + ((u >> 16) & 1u);           // RNE
  return (unsigned short)(u >> 16);
}

static __device__ __forceinline__ unsigned int pk2(float a, float b){
  return (unsigned int)f2bf(a) | ((unsigned int)f2bf(b) << 16);
}

static __device__ __forceinline__ short4v pack4(float4v v){
  uint2v u; u.x = pk2(v[0], v[1]); u.y = pk2(v[2], v[3]);
  return __builtin_bit_cast(short4v, u);
}

static __device__ __forceinline__ short8 pack8(float4v a, float4v b){
  uint4v u; u.x = pk2(a[0],a[1]); u.y = pk2(a[2],a[3]);
  u.z = pk2(b[0],b[1]); u.w = pk2(b[2],b[3]);
  return __builtin_bit_cast(short8, u);
}

// ------- kernel 0: WT[z][p][d] bf16 (Wq pre-scaled by C2) + maskf transpose -------
__global__ void prep(const float* __restrict__ Wq, const float* __restrict__ Wk,
                     const float* __restrict__ Wv, const int* __restrict__ mask,
                     uint16_t* __restrict__ WT, float* __restrict__ maskf){
  int idx = blockIdx.x*256 + threadIdx.x;      // 640*256 = 163840
  if (idx < 3*P_*D_){                          // 98304: weight transpose+cast
    int d = idx & (D_-1);
    int p = (idx >> 7) & (P_-1);
    int z = idx >> 15;
    const float* W = (z==0) ? Wq : (z==1) ? Wk : Wv;
    float sc = (z==0) ? C2 : 1.0f;
    WT[idx] = f2bf(W[d*P_ + p] * sc);
  } else {                                     // 65536: mask -> maskf[(b*M+m)*T+s]
    int j = idx - 3*P_*D_;
    int s = j & (T_-1);
    int bm = j >> 9;
    int b = bm >> 4, m = bm & (M_-1);
    maskf[j] = mask[(b*T_ + s)*M_ + m] ? 0.0f : -1e30f;
  }
}

// ---------------- kernel 1: QKV projection (bf16 MFMA, no LDS) --------------
// A = WT rows (p on reg axis), B = inp rows (t on lane axis) -> b64 stores
// out layout: QKV[z][g][t][e] bf16,  g=(b*M+m)*H+h.  Q pre-scaled by C2 (via WT/bias).
__global__ __launch_bounds__(256) void qkv_gemm(
    const float* __restrict__ inp, const uint16_t* __restrict__ WT,
    const float* __restrict__ bq, const float* __restrict__ bk,
    const float* __restrict__ bv, uint16_t* __restrict__ QKV){
  const int rb   = blockIdx.x;          // 64-row block (1024 blocks)
  const int z    = blockIdx.y;          // q/k/v
  const int tid  = threadIdx.x;
  const int wave = tid >> 6, lane = tid & 63;
  const int q4 = lane >> 4, c = lane & 15;

  const float* bias = (z==0) ? bq : (z==1) ? bk : bv;
  uint16_t* Out = QKV + (size_t)z * ((size_t)G_*T_*E_);
  const uint16_t* WTz = WT + (size_t)z * P_ * D_;
  const int row0 = rb*64;
  const int colbase = wave*64;

  // A-fragments: W^T[p][d], 16B contiguous along d  (L2-resident)
  short8 wfrag[4][4];
  for (int nj=0; nj<4; nj++){
    int p = colbase + nj*16 + c;
    for (int kc=0; kc<4; kc++)
      wfrag[nj][kc] = *(const short8*)(WTz + (size_t)p*D_ + kc*32 + q4*8);
  }

  float4v zf = {0.f,0.f,0.f,0.f};
  float4v acc[4][4];
  for (int i=0;i<4;i++) for (int j=0;j<4;j++) acc[i][j] = zf;

  for (int kc=0; kc<4; kc++){
    short8 afrag[4];
    for (int ti=0; ti<4; ti++){
      const float* src = inp + (size_t)(row0 + ti*16 + c)*D_ + kc*32 + q4*8;
      float4v x0 = *(const float4v*)src;
      float4v x1 = *(const float4v*)(src+4);
      afrag[ti] = pack8(x0, x1);
    }
    for (int ti=0; ti<4; ti++)
      for (int nj=0; nj<4; nj++)
        acc[ti][nj] = MFMA32(wfrag[nj][kc], afrag[ti], acc[ti][nj]);  // m=p(reg), n=t(lane)
  }

  // epilogue: +bias, ->bf16, b64 stores (4 consecutive e per lane)
  const float bs = (z==0) ? C2 : 1.0f;
  for (int nj=0; nj<4; nj++){
    float4v b4 = *(const float4v*)(bias + colbase + nj*16 + q4*4);
    b4 *= bs;
    const int h  = wave*2 + (nj>>1);
    const int e0 = (nj&1)*16 + q4*4;
    for (int ti=0; ti<4; ti++){
      int bt = rb*4 + ti;                       // row>>4 : b*T + t
      int t = bt & (T_-1);
      int b = bt >> 9;
      int g = (b*M_ + c)*H_ + h;                // m = c
      float4v v = acc[ti][nj] + b4;
      short4v pk = pack4(v);
      *(short4v*)(Out + ((size_t)g*T_ + t)*E_ + e0) = pk;
    }
  }
}

// ---------------- kernel 2: masked attention per (g, t-half) ---------------
// S^T = K.Q^T (C-layout: s on regs, t on lanes) -> exp2 -> direct K=16 PV MFMA
// (S^T C-layout IS the A-layout of 16x16x16 MFMA: zero movement for P).
// Denominator l via MFMA with all-ones B (row-sum broadcast, same layout as O).
#define VPAD 516   // Vt row stride (bf16): 258 dwords
#define OLS  36    // staged-O row stride (f32)

__global__ __launch_bounds__(256, 4) void attn(
    const uint16_t* __restrict__ QKV, const float* __restrict__ maskf,
    float* __restrict__ out){
  __shared__ __align__(16) char smem[E_*VPAD*2 > 256*OLS*4 ? E_*VPAD*2 + T_*4 : 256*OLS*4 + T_*4];
  uint16_t* Vt    = (uint16_t*)smem;               // 33,024 B  V^T[e][s]
  float*    maskc = (float*)(smem + E_*VPAD*2);    //  2,048 B  0 / -1e30
  float*    OL    = (float*)smem;                  // 36,864 B  (reused after loop)

  const int g    = blockIdx.x >> 1;
  const int half = blockIdx.x & 1;
  const int h = g & (H_-1), bm = g >> 3, m = bm & (M_-1), b = bm >> 4;
  const int tid = threadIdx.x;
  const int wave = tid >> 6, lane = tid & 63;
  const int q4 = lane >> 4, c = lane & 15;

  const uint16_t* Q = QKV + (size_t)g*T_*E_;
  const uint16_t* K = QKV + (size_t)G_*T_*E_   + (size_t)g*T_*E_;
  const uint16_t* V = QKV + (size_t)2*G_*T_*E_ + (size_t)g*T_*E_;

  // fills: maskc coalesced; Vt transposed via dword pairs (2-way banks = free)
  for (int s = tid; s < T_; s += 256)
    maskc[s] = maskf[(size_t)(b*M_ + m)*T_ + s];
  const uint32_t* V32 = (const uint32_t*)V;
  for (int k = tid; k < 4096; k += 256){
    int ep = k & 15;            // e-pair
    int s2 = k >> 4;            // s-pair
    uint32_t u0 = V32[(2*s2)*16 + ep];
    uint32_t u1 = V32[(2*s2+1)*16 + ep];
    *(uint32_t*)(Vt + (2*ep  )*VPAD + 2*s2) = (u0 & 0xffffu) | (u1 << 16);
    *(uint32_t*)(Vt + (2*ep+1)*VPAD + 2*s2) = (u0 >> 16) | (u1 & 0xffff0000u);
  }

  const int t0 = half*256 + wave*64;
  short8 qfrag[4];                       // B-operand: Q[t][e]
  for (int tj=0; tj<4; tj++)
    qfrag[tj] = *(const short8*)(Q + (size_t)(t0 + tj*16 + c)*E_ + q4*8);
  __syncthreads();

  float4v zf = {0.f,0.f,0.f,0.f};
  float4v O[4][2];
  float4v L4[4];
  for (int i=0;i<4;i++){ O[i][0]=zf; O[i][1]=zf; L4[i]=zf; }
  const short one_bf = (short)0x3F80;
  short4v ones; ones[0]=one_bf; ones[1]=one_bf; ones[2]=one_bf; ones[3]=one_bf;

  for (int sb = 0; sb < 16; sb++){
    const int s0 = sb*32;
    short8 kfrag[2];                     // A-operand: K[s][e]
    kfrag[0] = *(const short8*)(K + (size_t)(s0 + c)*E_ + q4*8);
    kfrag[1] = *(const short8*)(K + (size_t)(s0 + 16 + c)*E_ + q4*8);

    short4v pk[2][4];
    for (int si=0; si<2; si++){
      float4v mm = *(const float4v*)(&maskc[s0 + si*16 + q4*4]);
      for (int tj=0; tj<4; tj++){
        float4v st = MFMA32(kfrag[si], qfrag[tj], zf);   // S^T: s on regs, t on lanes
        float4v p;
        p[0] = EXP2F(st[0] + mm[0]);     // scale pre-folded into Q
        p[1] = EXP2F(st[1] + mm[1]);
        p[2] = EXP2F(st[2] + mm[2]);
        p[3] = EXP2F(st[3] + mm[3]);
        pk[si][tj] = pack4(p);
      }
    }
    // O += P.V ; L += P.1   (P regs feed K=16 A-operand directly)
    for (int si=0; si<2; si++){
      short4v vf0 = *(const short4v*)(Vt + (size_t)c*VPAD      + s0 + si*16 + q4*4);
      short4v vf1 = *(const short4v*)(Vt + (size_t)(16+c)*VPAD + s0 + si*16 + q4*4);
      for (int ti=0; ti<4; ti++){
        O[ti][0] = MFMA16(pk[si][ti], vf0, O[ti][0]);
        O[ti][1] = MFMA16(pk[si][ti], vf1, O[ti][1]);
        L4[ti]   = MFMA16(pk[si][ti], ones, L4[ti]);
      }
    }
  }

  // normalize in-register (L4 has row-sum broadcast, same reg-layout as O)
  __syncthreads();                        // all waves done reading Vt
  for (int ti=0; ti<4; ti++){
    float4v linv;
    for (int r=0; r<4; r++) linv[r] = __builtin_amdgcn_rcpf(L4[ti][r]);
    for (int ej=0; ej<2; ej++){
      float4v v = O[ti][ej] * linv;
      int tl = wave*64 + ti*16 + q4*4;    // t-local base
      for (int r=0; r<4; r++)
        OL[(tl + r)*OLS + ej*16 + c] = v[r];
    }
  }
  __syncthreads();

  // coalesced f32x4 stores: 256 rows x 32 e
  for (int k = 0; k < 8; k++){
    int iter = tid + k*256;
    int tl = iter >> 3, q = iter & 7;
    int t = half*256 + tl;
    float4v v = *(const float4v*)(&OL[tl*OLS + q*4]);
    *(float4v*)(out + (((size_t)b*T_ + t)*M_ + m)*P_ + h*E_ + q*4) = v;
  }
}

extern "C" void kernel_launch(void* const* d_in, const int* in_sizes, int n_in,
                              void* d_out, int out_size, void* d_ws, size_t ws_size,
                              hipStream_t stream){
  const float* inp = (const float*)d_in[0];
  const int*   msk = (const int*)  d_in[1];
  const float* Wq  = (const float*)d_in[2];
  const float* bq  = (const float*)d_in[3];
  const float* Wk  = (const float*)d_in[4];
  const float* bk  = (const float*)d_in[5];
  const float* Wv  = (const float*)d_in[6];
  const float* bv  = (const float*)d_in[7];
  float* out = (float*)d_out;

  uint16_t* WT    = (uint16_t*)d_ws;                       // 196,608 B
  float*    maskf = (float*)((char*)d_ws + 196608);        // 262,144 B
  uint16_t* QKV   = (uint16_t*)((char*)d_ws + 458752);     // 3 * 32 MiB bf16

  prep<<<dim3(640), dim3(256), 0, stream>>>(Wq, Wk, Wv, msk, WT, maskf);
  qkv_gemm<<<dim3(1024,3), dim3(256), 0, stream>>>(inp, WT, bq, bk, bv, QKV);
  attn<<<dim3(2048), dim3(256), 0, stream>>>(QKV, maskf, out);
}

// Round 5
// 235.103 us; speedup vs baseline: 1.1232x; 1.0648x over previous
//
#include <hip/hip_runtime.h>
#include <stdint.h>

#define B_ 8
#define T_ 512
#define M_ 16
#define D_ 128
#define P_ 256
#define H_ 8
#define E_ 32
#define G_ (B_*M_*H_)   // 1024 (b,m,h) groups

typedef __attribute__((ext_vector_type(8))) short  short8;
typedef __attribute__((ext_vector_type(4))) short  short4v;
typedef __attribute__((ext_vector_type(4))) float  float4v;
typedef __attribute__((ext_vector_type(2))) unsigned int uint2v;
typedef __attribute__((ext_vector_type(4))) unsigned int uint4v;
typedef __attribute__((ext_vector_type(2))) __bf16 bf16x2;

#define MFMA32(a,b,c) __builtin_amdgcn_mfma_f32_16x16x32_bf16(a,b,c,0,0,0)   // K=32, short8 ops
#define MFMA16(a,b,c) __builtin_amdgcn_mfma_f32_16x16x16bf16_1k(a,b,c,0,0,0) // K=16, short4 ops
#define EXP2F(x) __builtin_amdgcn_exp2f(x)

#define C2 0.2550332772062413f   // log2(e)/sqrt(E)

#if defined(__has_builtin)
# if __has_builtin(__builtin_amdgcn_cvt_pk_bf16_f32)
#  define HAVE_CVT_PK 1
# endif
#endif

static __device__ __forceinline__ unsigned short f2bf(float x){
  unsigned int u = __builtin_bit_cast(unsigned int, x);
  u += 0x7FFFu + ((u >> 16) & 1u);           // RNE
  return (unsigned short)(u >> 16);
}

static __device__ __forceinline__ unsigned int pk2(float a, float b){
#ifdef HAVE_CVT_PK
  bf16x2 h = __builtin_amdgcn_cvt_pk_bf16_f32(a, b);   // v_cvt_pk_bf16_f32 (RNE)
  return __builtin_bit_cast(unsigned int, h);
#else
  return (unsigned int)f2bf(a) | ((unsigned int)f2bf(b) << 16);
#endif
}

static __device__ __forceinline__ short4v pack4(float4v v){
  uint2v u; u.x = pk2(v[0], v[1]); u.y = pk2(v[2], v[3]);
  return __builtin_bit_cast(short4v, u);
}

static __device__ __forceinline__ short8 pack8(float4v a, float4v b){
  uint4v u; u.x = pk2(a[0],a[1]); u.y = pk2(a[2],a[3]);
  u.z = pk2(b[0],b[1]); u.w = pk2(b[2],b[3]);
  return __builtin_bit_cast(short8, u);
}

// ------- kernel 0: WT[z][p][d] bf16 (Wq pre-scaled by C2) + maskf transpose -------
__global__ void prep(const float* __restrict__ Wq, const float* __restrict__ Wk,
                     const float* __restrict__ Wv, const int* __restrict__ mask,
                     uint16_t* __restrict__ WT, float* __restrict__ maskf){
  int idx = blockIdx.x*256 + threadIdx.x;      // 640*256 = 163840
  if (idx < 3*P_*D_){                          // 98304: weight transpose+cast
    int d = idx & (D_-1);
    int p = (idx >> 7) & (P_-1);
    int z = idx >> 15;
    const float* W = (z==0) ? Wq : (z==1) ? Wk : Wv;
    float sc = (z==0) ? C2 : 1.0f;
    WT[idx] = f2bf(W[d*P_ + p] * sc);
  } else {                                     // 65536: mask -> maskf[(b*M+m)*T+s]
    int j = idx - 3*P_*D_;
    int s = j & (T_-1);
    int bm = j >> 9;
    int b = bm >> 4, m = bm & (M_-1);
    maskf[j] = mask[(b*T_ + s)*M_ + m] ? 0.0f : -1e30f;
  }
}

// ---------------- kernel 1: QKV projection, z-loop inside block --------------
// 2048 blocks x 32 rows. afrag (inp, bf16-packed) persistent across z.
// Epilogue staged through XOR-swizzled LDS -> 128B-contiguous global runs.
// out layout: QKV[z][g][t][e] bf16,  g=(b*M+m)*H+h.  Q pre-scaled by C2.
__global__ __launch_bounds__(256, 4) void qkv_gemm(
    const float* __restrict__ inp, const uint16_t* __restrict__ WT,
    const float* __restrict__ bq, const float* __restrict__ bk,
    const float* __restrict__ bv, uint16_t* __restrict__ QKV){
  __shared__ __align__(16) uint16_t SQ[32*256];   // 16 KB, XOR-swizzled 16B chunks
  const int rb   = blockIdx.x;          // 32-row block (2048 blocks)
  const int tid  = threadIdx.x;
  const int wave = tid >> 6, lane = tid & 63;
  const int q4 = lane >> 4, c = lane & 15;
  const int row0 = rb*32;
  const int colbase = wave*64;

  // afrag: pack inp rows once (held across all 3 z)
  short8 afrag[4][2];
  for (int kc=0; kc<4; kc++)
    for (int ti=0; ti<2; ti++){
      const float* src = inp + (size_t)(row0 + ti*16 + c)*D_ + kc*32 + q4*8;
      float4v x0 = *(const float4v*)src;
      float4v x1 = *(const float4v*)(src+4);
      afrag[kc][ti] = pack8(x0, x1);
    }

  for (int z = 0; z < 3; z++){
    const float* bias = (z==0) ? bq : (z==1) ? bk : bv;
    const float bs = (z==0) ? C2 : 1.0f;
    uint16_t* Out = QKV + (size_t)z * ((size_t)G_*T_*E_);
    const uint16_t* WTz = WT + (size_t)z * P_ * D_;

    float4v zf = {0.f,0.f,0.f,0.f};
    float4v acc[2][4];
    for (int i=0;i<2;i++) for (int j=0;j<4;j++) acc[i][j] = zf;

    for (int kc=0; kc<4; kc++){
      short8 wfrag[4];                 // A-operand: W^T[p][d], L2-hot
      for (int nj=0; nj<4; nj++)
        wfrag[nj] = *(const short8*)(WTz + (size_t)(colbase + nj*16 + c)*D_ + kc*32 + q4*8);
      for (int ti=0; ti<2; ti++)
        for (int nj=0; nj<4; nj++)
          acc[ti][nj] = MFMA32(wfrag[nj], afrag[kc][ti], acc[ti][nj]);  // m=p(reg), n=row(lane)
    }

    if (z) __syncthreads();            // prior store-out reads done before overwrite
    // stage to LDS: value at (row = ti*16+c, pcol = colbase+nj*16+q4*4 .. +3)
    for (int nj=0; nj<4; nj++){
      float4v b4 = *(const float4v*)(bias + colbase + nj*16 + q4*4);
      b4 *= bs;
      const int chunk = wave*8 + nj*2 + (q4>>1);     // 16B chunk index 0..31
      for (int ti=0; ti<2; ti++){
        int row = ti*16 + c;
        int sw = chunk ^ row;                        // row&31 == row
        short4v pk = pack4(acc[ti][nj] + b4);
        *(short4v*)(SQ + row*256 + sw*8 + (q4&1)*4) = pk;
      }
    }
    __syncthreads();

    // store-out: 4 rounds x (8 lanes x 16B = 128B contiguous per (m,h))
    const int l  = tid & 7;
    const int toff = l >> 2, ec = l & 3;             // t-offset, e-chunk
    int bt = rb*2 + toff;
    int t = bt & (T_-1), b = bt >> 9;
    for (int rnd = 0; rnd < 4; rnd++){
      int mh = rnd*32 + (tid >> 3);
      int m = mh & 15, h = mh >> 4;
      int row = toff*16 + m;
      int sw = (h*4 + ec) ^ row;
      uint4v v = *(const uint4v*)(SQ + row*256 + sw*8);
      int g = (b*M_ + m)*H_ + h;
      *(uint4v*)(Out + ((size_t)g*T_ + t)*E_ + ec*8) = v;
    }
    __syncthreads();                   // writes of this z visible/done before next z reuses
  }
}

// ---------------- kernel 2: masked attention per (g, t-half) ---------------
// S^T = K.Q^T (C-layout: s on regs, t on lanes) -> exp2 -> direct K=16 PV MFMA
// (S^T C-layout IS the A-layout of 16x16x16 MFMA: zero movement for P).
// Denominator l via MFMA with all-ones B (row-sum broadcast, same layout as O).
#define VPAD 516   // Vt row stride (bf16): 258 dwords
#define OLS  36    // staged-O row stride (f32)

__global__ __launch_bounds__(256, 4) void attn(
    const uint16_t* __restrict__ QKV, const float* __restrict__ maskf,
    float* __restrict__ out){
  __shared__ __align__(16) char smem[E_*VPAD*2 > 256*OLS*4 ? E_*VPAD*2 + T_*4 : 256*OLS*4 + T_*4];
  uint16_t* Vt    = (uint16_t*)smem;               // 33,024 B  V^T[e][s]
  float*    maskc = (float*)(smem + E_*VPAD*2);    //  2,048 B  0 / -1e30
  float*    OL    = (float*)smem;                  // 36,864 B  (reused after loop)

  const int g    = blockIdx.x >> 1;
  const int half = blockIdx.x & 1;
  const int h = g & (H_-1), bm = g >> 3, m = bm & (M_-1), b = bm >> 4;
  const int tid = threadIdx.x;
  const int wave = tid >> 6, lane = tid & 63;
  const int q4 = lane >> 4, c = lane & 15;

  const uint16_t* Q = QKV + (size_t)g*T_*E_;
  const uint16_t* K = QKV + (size_t)G_*T_*E_   + (size_t)g*T_*E_;
  const uint16_t* V = QKV + (size_t)2*G_*T_*E_ + (size_t)g*T_*E_;

  // fills: maskc coalesced; Vt transposed via dword pairs (2-way banks = free)
  for (int s = tid; s < T_; s += 256)
    maskc[s] = maskf[(size_t)(b*M_ + m)*T_ + s];
  const uint32_t* V32 = (const uint32_t*)V;
  for (int k = tid; k < 4096; k += 256){
    int ep = k & 15;            // e-pair
    int s2 = k >> 4;            // s-pair
    uint32_t u0 = V32[(2*s2)*16 + ep];
    uint32_t u1 = V32[(2*s2+1)*16 + ep];
    *(uint32_t*)(Vt + (2*ep  )*VPAD + 2*s2) = (u0 & 0xffffu) | (u1 << 16);
    *(uint32_t*)(Vt + (2*ep+1)*VPAD + 2*s2) = (u0 >> 16) | (u1 & 0xffff0000u);
  }

  const int t0 = half*256 + wave*64;
  short8 qfrag[4];                       // B-operand: Q[t][e]
  for (int tj=0; tj<4; tj++)
    qfrag[tj] = *(const short8*)(Q + (size_t)(t0 + tj*16 + c)*E_ + q4*8);
  __syncthreads();

  float4v zf = {0.f,0.f,0.f,0.f};
  float4v O[4][2];
  float4v L4[4];
  for (int i=0;i<4;i++){ O[i][0]=zf; O[i][1]=zf; L4[i]=zf; }
  const short one_bf = (short)0x3F80;
  short4v ones; ones[0]=one_bf; ones[1]=one_bf; ones[2]=one_bf; ones[3]=one_bf;

  for (int sb = 0; sb < 16; sb++){
    const int s0 = sb*32;
    short8 kfrag[2];                     // A-operand: K[s][e]
    kfrag[0] = *(const short8*)(K + (size_t)(s0 + c)*E_ + q4*8);
    kfrag[1] = *(const short8*)(K + (size_t)(s0 + 16 + c)*E_ + q4*8);

    short4v pk[2][4];
    for (int si=0; si<2; si++){
      float4v mm = *(const float4v*)(&maskc[s0 + si*16 + q4*4]);
      for (int tj=0; tj<4; tj++){
        float4v st = MFMA32(kfrag[si], qfrag[tj], zf);   // S^T: s on regs, t on lanes
        float4v p;
        p[0] = EXP2F(st[0] + mm[0]);     // scale pre-folded into Q
        p[1] = EXP2F(st[1] + mm[1]);
        p[2] = EXP2F(st[2] + mm[2]);
        p[3] = EXP2F(st[3] + mm[3]);
        pk[si][tj] = pack4(p);
      }
    }
    // O += P.V ; L += P.1   (P regs feed K=16 A-operand directly)
    for (int si=0; si<2; si++){
      short4v vf0 = *(const short4v*)(Vt + (size_t)c*VPAD      + s0 + si*16 + q4*4);
      short4v vf1 = *(const short4v*)(Vt + (size_t)(16+c)*VPAD + s0 + si*16 + q4*4);
      for (int ti=0; ti<4; ti++){
        O[ti][0] = MFMA16(pk[si][ti], vf0, O[ti][0]);
        O[ti][1] = MFMA16(pk[si][ti], vf1, O[ti][1]);
        L4[ti]   = MFMA16(pk[si][ti], ones, L4[ti]);
      }
    }
  }

  // normalize in-register (L4 has row-sum broadcast, same reg-layout as O)
  __syncthreads();                        // all waves done reading Vt
  for (int ti=0; ti<4; ti++){
    float4v linv;
    for (int r=0; r<4; r++) linv[r] = __builtin_amdgcn_rcpf(L4[ti][r]);
    for (int ej=0; ej<2; ej++){
      float4v v = O[ti][ej] * linv;
      int tl = wave*64 + ti*16 + q4*4;    // t-local base
      for (int r=0; r<4; r++)
        OL[(tl + r)*OLS + ej*16 + c] = v[r];
    }
  }
  __syncthreads();

  // coalesced f32x4 stores: 256 rows x 32 e
  for (int k = 0; k < 8; k++){
    int iter = tid + k*256;
    int tl = iter >> 3, q = iter & 7;
    int t = half*256 + tl;
    float4v v = *(const float4v*)(&OL[tl*OLS + q*4]);
    *(float4v*)(out + (((size_t)b*T_ + t)*M_ + m)*P_ + h*E_ + q*4) = v;
  }
}

extern "C" void kernel_launch(void* const* d_in, const int* in_sizes, int n_in,
                              void* d_out, int out_size, void* d_ws, size_t ws_size,
                              hipStream_t stream){
  const float* inp = (const float*)d_in[0];
  const int*   msk = (const int*)  d_in[1];
  const float* Wq  = (const float*)d_in[2];
  const float* bq  = (const float*)d_in[3];
  const float* Wk  = (const float*)d_in[4];
  const float* bk  = (const float*)d_in[5];
  const float* Wv  = (const float*)d_in[6];
  const float* bv  = (const float*)d_in[7];
  float* out = (float*)d_out;

  uint16_t* WT    = (uint16_t*)d_ws;                       // 196,608 B
  float*    maskf = (float*)((char*)d_ws + 196608);        // 262,144 B
  uint16_t* QKV   = (uint16_t*)((char*)d_ws + 458752);     // 3 * 32 MiB bf16

  prep<<<dim3(640), dim3(256), 0, stream>>>(Wq, Wk, Wv, msk, WT, maskf);
  qkv_gemm<<<dim3(2048), dim3(256), 0, stream>>>(inp, WT, bq, bk, bv, QKV);
  attn<<<dim3(2048), dim3(256), 0, stream>>>(QKV, maskf, out);
}

// Round 6
// 200.257 us; speedup vs baseline: 1.3187x; 1.1740x over previous
//
#include <hip/hip_runtime.h>
#include <stdint.h>

#define B_ 8
#define T_ 512
#define M_ 16
#define D_ 128
#define P_ 256
#define H_ 8
#define E_ 32

typedef __attribute__((ext_vector_type(8))) short  short8;
typedef __attribute__((ext_vector_type(4))) short  short4v;
typedef __attribute__((ext_vector_type(4))) float  float4v;
typedef __attribute__((ext_vector_type(2))) unsigned int uint2v;
typedef __attribute__((ext_vector_type(4))) unsigned int uint4v;
typedef __attribute__((ext_vector_type(2))) __bf16 bf16x2;

#define MFMA32(a,b,c) __builtin_amdgcn_mfma_f32_16x16x32_bf16(a,b,c,0,0,0)   // K=32, short8 ops
#define MFMA16(a,b,c) __builtin_amdgcn_mfma_f32_16x16x16bf16_1k(a,b,c,0,0,0) // K=16, short4 ops
#define EXP2F(x) __builtin_amdgcn_exp2f(x)

#define C2 0.2550332772062413f   // log2(e)/sqrt(E)

#if defined(__has_builtin)
# if __has_builtin(__builtin_amdgcn_cvt_pk_bf16_f32)
#  define HAVE_CVT_PK 1
# endif
#endif

static __device__ __forceinline__ unsigned short f2bf(float x){
  unsigned int u = __builtin_bit_cast(unsigned int, x);
  u += 0x7FFFu + ((u >> 16) & 1u);           // RNE
  return (unsigned short)(u >> 16);
}

static __device__ __forceinline__ unsigned int pk2(float a, float b){
#ifdef HAVE_CVT_PK
  bf16x2 h = __builtin_amdgcn_cvt_pk_bf16_f32(a, b);   // v_cvt_pk_bf16_f32 (RNE)
  return __builtin_bit_cast(unsigned int, h);
#else
  return (unsigned int)f2bf(a) | ((unsigned int)f2bf(b) << 16);
#endif
}

static __device__ __forceinline__ short4v pack4(float4v v){
  uint2v u; u.x = pk2(v[0], v[1]); u.y = pk2(v[2], v[3]);
  return __builtin_bit_cast(short4v, u);
}

static __device__ __forceinline__ short8 pack8(float4v a, float4v b){
  uint4v u; u.x = pk2(a[0],a[1]); u.y = pk2(a[2],a[3]);
  u.z = pk2(b[0],b[1]); u.w = pk2(b[2],b[3]);
  return __builtin_bit_cast(short8, u);
}

// ------- kernel 0: WT[z][p][d] bf16 (Wq pre-scaled by C2) + maskf transpose -------
__global__ void prep(const float* __restrict__ Wq, const float* __restrict__ Wk,
                     const float* __restrict__ Wv, const int* __restrict__ mask,
                     uint16_t* __restrict__ WT, float* __restrict__ maskf){
  int idx = blockIdx.x*256 + threadIdx.x;      // 640*256 = 163840
  if (idx < 3*P_*D_){                          // 98304: weight transpose+cast
    int d = idx & (D_-1);
    int p = (idx >> 7) & (P_-1);
    int z = idx >> 15;
    const float* W = (z==0) ? Wq : (z==1) ? Wk : Wv;
    float sc = (z==0) ? C2 : 1.0f;
    WT[idx] = f2bf(W[d*P_ + p] * sc);
  } else {                                     // 65536: mask -> maskf[(b*M+m)*T+s]
    int j = idx - 3*P_*D_;
    int s = j & (T_-1);
    int bm = j >> 9;
    int b = bm >> 4, m = bm & (M_-1);
    maskf[j] = mask[(b*T_ + s)*M_ + m] ? 0.0f : -1e30f;
  }
}

// ---------------- fused QKV + masked attention, one block per (b,m,h) ------
// Wave w owns rows [64w,64w+64): same inp rows serve as Q's t and K/V's s.
// Proj MFMA C-layout (reg r -> e=q4*4+r, lane -> row) IS the A/B operand
// layout of the K=16 MFMA -> Q stays in regs, K goes to LDS [s][e], V to
// LDS transposed [e][s]. Mask folds into the C operand of the S^T chain.
__global__ __launch_bounds__(512, 4) void attn_fused(
    const float* __restrict__ inp, const uint16_t* __restrict__ WT,
    const float* __restrict__ bq, const float* __restrict__ bk,
    const float* __restrict__ bv, const float* __restrict__ maskf,
    float* __restrict__ out){
  __shared__ __align__(16) uint16_t Kb[T_*E_];   // 32768 B  K[s][e], chunk-swizzled
  __shared__ __align__(16) uint16_t Vt[E_*T_];   // 32768 B  V^T[e][s], u-swizzled

  const int bx = blockIdx.x;                // 1024
  const int h = bx >> 7, bm = bx & 127;     // same-bm blocks -> same XCD (bx%8 = bm%8)
  const int b = bm >> 4, m = bm & 15;
  const int tid = threadIdx.x;
  const int wave = tid >> 6, lane = tid & 63;
  const int q4 = lane >> 4, c = lane & 15;
  const int t0 = wave*64;

  // ---- pack inp rows once: rows t0+tj*16+c, full d ----
  short8 af[4][4];   // [tj][kc]
  for (int tj=0; tj<4; tj++){
    const float* src = inp + (size_t)((b*T_ + t0 + tj*16 + c)*M_ + m)*D_;
    for (int kc=0; kc<4; kc++){
      float4v x0 = *(const float4v*)(src + kc*32 + q4*8);
      float4v x1 = *(const float4v*)(src + kc*32 + q4*8 + 4);
      af[tj][kc] = pack8(x0, x1);
    }
  }

  const uint16_t* WQ = WT                       + (size_t)(h*E_)*D_;
  const uint16_t* WK = WT + (size_t)1*P_*D_     + (size_t)(h*E_)*D_;
  const uint16_t* WV = WT + (size_t)2*P_*D_     + (size_t)(h*E_)*D_;
  float4v zf = {0.f,0.f,0.f,0.f};

  // ---- K projection -> Kb[s][e] (b64 writes, chunk swizzle) ----
  for (int eh=0; eh<2; eh++){
    float4v ka[4]; for (int j=0;j<4;j++) ka[j]=zf;
    for (int kc=0; kc<4; kc++){
      short8 w = *(const short8*)(WK + (size_t)(eh*16 + c)*D_ + kc*32 + q4*8);
      for (int sj=0; sj<4; sj++) ka[sj] = MFMA32(w, af[sj][kc], ka[sj]);
    }
    float4v bk4 = *(const float4v*)(bk + h*E_ + eh*16 + q4*4);
    for (int sj=0; sj<4; sj++){
      int s = t0 + sj*16 + c;
      short4v kv = pack4(ka[sj] + bk4);
      *(short4v*)(Kb + s*32 + ((4*eh + q4 + s) & 7)*4) = kv;
    }
  }
  // ---- V projection -> Vt[e][s] (scalar b16 transpose writes) ----
  for (int eh=0; eh<2; eh++){
    float4v va[4]; for (int j=0;j<4;j++) va[j]=zf;
    for (int kc=0; kc<4; kc++){
      short8 w = *(const short8*)(WV + (size_t)(eh*16 + c)*D_ + kc*32 + q4*8);
      for (int sj=0; sj<4; sj++) va[sj] = MFMA32(w, af[sj][kc], va[sj]);
    }
    float4v bv4 = *(const float4v*)(bv + h*E_ + eh*16 + q4*4);
    for (int sj=0; sj<4; sj++){
      int s = t0 + sj*16 + c;
      short4v vv = pack4(va[sj] + bv4);
      for (int r=0; r<4; r++){
        int e = eh*16 + q4*4 + r;
        Vt[e*T_ + ((((s>>2) + e) & 127)*4) + (s&3)] = (uint16_t)vv[r];
      }
    }
  }
  // ---- Q projection -> qb regs (C-layout == MFMA16 B-operand layout) ----
  short4v qb[4][2];
  for (int eh=0; eh<2; eh++){
    float4v qa[4]; for (int j=0;j<4;j++) qa[j]=zf;
    for (int kc=0; kc<4; kc++){
      short8 w = *(const short8*)(WQ + (size_t)(eh*16 + c)*D_ + kc*32 + q4*8);
      for (int tj=0; tj<4; tj++) qa[tj] = MFMA32(w, af[tj][kc], qa[tj]);
    }
    float4v bq4 = *(const float4v*)(bq + h*E_ + eh*16 + q4*4);
    bq4 *= C2;
    for (int tj=0; tj<4; tj++) qb[tj][eh] = pack4(qa[tj] + bq4);
  }
  __syncthreads();

  // ---- s-loop: S^T = K.Q^T (mask as C operand) -> exp2 -> PV ----
  float4v O[4][2], L4[4];
  for (int i=0;i<4;i++){ O[i][0]=zf; O[i][1]=zf; L4[i]=zf; }
  const short one_bf = (short)0x3F80;
  short4v ones; ones[0]=one_bf; ones[1]=one_bf; ones[2]=one_bf; ones[3]=one_bf;
  const float* mrow = maskf + (size_t)bm*T_;

  for (int sb=0; sb<16; sb++){
    for (int si=0; si<2; si++){
      const int sq = sb*32 + si*16;
      float4v mm = *(const float4v*)(mrow + sq + q4*4);
      const int srow = sq + c;
      short4v kb0 = *(const short4v*)(Kb + srow*32 + ((    q4 + srow) & 7)*4);  // e 0..15
      short4v kb1 = *(const short4v*)(Kb + srow*32 + ((4 + q4 + srow) & 7)*4);  // e 16..31
      const int u = (sq >> 2) + q4;
      short4v vf0 = *(const short4v*)(Vt + (size_t)c*T_      + ((u + c     ) & 127)*4);
      short4v vf1 = *(const short4v*)(Vt + (size_t)(16+c)*T_ + ((u + 16 + c) & 127)*4);
      for (int tj=0; tj<4; tj++){
        float4v st = MFMA16(kb1, qb[tj][1], MFMA16(kb0, qb[tj][0], mm));
        float4v p;
        p[0] = EXP2F(st[0]);
        p[1] = EXP2F(st[1]);
        p[2] = EXP2F(st[2]);
        p[3] = EXP2F(st[3]);
        short4v pf = pack4(p);
        O[tj][0] = MFMA16(pf, vf0, O[tj][0]);
        O[tj][1] = MFMA16(pf, vf1, O[tj][1]);
        L4[tj]   = MFMA16(pf, ones, L4[tj]);
      }
    }
  }

  // ---- normalize + direct stores (lane = e, regs = t) ----
  for (int ti=0; ti<4; ti++){
    float4v linv;
    for (int r=0; r<4; r++) linv[r] = __builtin_amdgcn_rcpf(L4[ti][r]);
    for (int ej=0; ej<2; ej++){
      float4v v = O[ti][ej] * linv;
      for (int r=0; r<4; r++){
        int t = t0 + ti*16 + q4*4 + r;
        out[(size_t)((b*T_ + t)*M_ + m)*P_ + h*E_ + ej*16 + c] = v[r];
      }
    }
  }
}

extern "C" void kernel_launch(void* const* d_in, const int* in_sizes, int n_in,
                              void* d_out, int out_size, void* d_ws, size_t ws_size,
                              hipStream_t stream){
  const float* inp = (const float*)d_in[0];
  const int*   msk = (const int*)  d_in[1];
  const float* Wq  = (const float*)d_in[2];
  const float* bq  = (const float*)d_in[3];
  const float* Wk  = (const float*)d_in[4];
  const float* bk  = (const float*)d_in[5];
  const float* Wv  = (const float*)d_in[6];
  const float* bv  = (const float*)d_in[7];
  float* out = (float*)d_out;

  uint16_t* WT    = (uint16_t*)d_ws;                       // 196,608 B
  float*    maskf = (float*)((char*)d_ws + 196608);        // 262,144 B

  prep<<<dim3(640), dim3(256), 0, stream>>>(Wq, Wk, Wv, msk, WT, maskf);
  attn_fused<<<dim3(1024), dim3(512), 0, stream>>>(inp, WT, bq, bk, bv, maskf, out);
}